// Round 8
// baseline (490.801 us; speedup 1.0000x reference)
//
#include <hip/hip_runtime.h>

// AttentionBasedNN: 4-layer additive attention + residual FCs + head.
// VEC=1280, HID=128, B=4, S=256. fp32 (no fp32 MFMA on CDNA4 -> vector ALU).
//
// Round-8: occupancy push. All heavy kernels launch >=512 blocks (2-4
// blocks/CU): QK/FC1/K4 split-K=16; PV 64x32 tiles (640 blocks); FC2 32x64
// tiles (640 blocks); scores 1 row/block (1024 blocks). FC1 accumulates
// directly into dense Hd via coalesced atomicAdd (zeroed in qksum), killing
// FC2's 8x partial A-reads. LN stays folded via stats (R7-proven).

#define DEV __device__ __forceinline__

static constexpr int VEC = 1280;
static constexpr int HID = 128;
static constexpr int BB  = 4;
static constexpr int SS  = 256;
static constexpr int MROWS = BB * SS;   // 1024
static constexpr int NPART = 16;        // split-K partials (QK, K4)
static constexpr float INV_VEC = 1.0f / 1280.0f;

DEV float ftanh(float x) {
  float e = __expf(2.0f * x);
  return 1.0f - __fdividef(2.0f, e + 1.0f);
}

DEV float waveSum(float v) {
#pragma unroll
  for (int off = 32; off > 0; off >>= 1) v += __shfl_xor(v, off, 64);
  return v;
}
DEV float waveMax(float v) {
#pragma unroll
  for (int off = 32; off > 0; off >>= 1) v = fmaxf(v, __shfl_xor(v, off, 64));
  return v;
}
// blockDim.x == 256 (4 waves) everywhere these are used.
DEV float blockSum(float v, float* red) {
  v = waveSum(v);
  int tid = threadIdx.x;
  if ((tid & 63) == 0) red[tid >> 6] = v;
  __syncthreads();
  float r = (red[0] + red[1]) + (red[2] + red[3]);
  __syncthreads();
  return r;
}
DEV float blockMax(float v, float* red) {
  v = waveMax(v);
  int tid = threadIdx.x;
  if ((tid & 63) == 0) red[tid >> 6] = v;
  __syncthreads();
  float r = fmaxf(fmaxf(red[0], red[1]), fmaxf(red[2], red[3]));
  __syncthreads();
  return r;
}

// ---------------------------------------------------------------------------
// fp32 GEMM, TM x TN tile, BK=16, 256 threads, MI x NJ microtile
// (16*MI==TM, 16*NJ==TN), register double-buffered staging.
// MODE 0 plain | 1 split-K (z: k-slice kChunk, C += z*sCb) | 2 batched
//      (z: A += z*sAb, B += z*sBb, C/res += z*sCb).
// ABR:  A = relu(A + aBias[k]) on load.
// ALN:  A = (A - mean[row])*rstd[row] from stats (row = m0+ar).
// OBIAS += oBias[n]. RESP += res[m][n]. RESLN += LN(res[m][n]) via stats.
// STATS: epilogue row sum/sumsq -> atomicAdd Ssum/Ssq (row = batchoff + m).
// CATOMIC: epilogue atomicAdd into C (dest pre-zeroed) instead of store.
// ---------------------------------------------------------------------------
template <int TM, int TN, int MI, int NJ, int MODE, bool ABR, bool ALN,
          bool OBIAS, bool RESLN, bool RESP, bool STATS, bool CATOMIC>
__global__ __launch_bounds__(256) void gemm_k(
    const float* __restrict__ A, long sAb,
    const float* __restrict__ B0, const float* __restrict__ B1, int nSplitB,
    long sBb, int ldB,
    float* __restrict__ C, long sCb,
    const float* __restrict__ aBias, const float* __restrict__ oBias,
    const float* __restrict__ res,
    float* __restrict__ Ssum, float* __restrict__ Ssq,
    int N, int K, int kChunk) {
  const int n0 = blockIdx.x * TN;
  const int m0 = blockIdx.y * TM;
  const int z  = blockIdx.z;

  const float* Ab = A + (MODE == 2 ? (long)z * sAb : 0L);
  float*       Cb = C + (MODE >= 1 ? (long)z * sCb : 0L);
  const float* resb = (RESP || RESLN)
                          ? (res + (MODE == 2 ? (long)z * sCb : 0L))
                          : nullptr;
  const float* Bsel;
  int nb;
  if (n0 < nSplitB) { Bsel = B0; nb = n0; } else { Bsel = B1; nb = n0 - nSplitB; }
  if (MODE == 2) Bsel += (long)z * sBb;

  const int kBeg = (MODE == 1) ? z * kChunk : 0;
  const int kEnd = (MODE == 1) ? kBeg + kChunk : K;

  __shared__ float As[16][TM + 4];  // [k][m]
  __shared__ float Bs[16][TN + 4];  // [k][n]

  const int tid = threadIdx.x;
  const int tx = tid & 15, ty = tid >> 4;
  // A staging: TM/16 floats per thread.
  const int ar = (TM == 64) ? (tid >> 2) : (tid >> 3);
  const int ac = (TM == 64) ? ((tid & 3) << 2) : ((tid & 7) << 1);
  // B staging: TN/16 floats per thread.
  const int br = tid >> 4;
  const int bc = (TN == 64) ? ((tid & 15) << 2) : ((tid & 15) << 1);

  float aMean = 0.0f, aRstd = 1.0f;
  if (ALN) {
    const int rm = m0 + ar;
    const float s = Ssum[rm], q = Ssq[rm];
    aMean = s * INV_VEC;
    aRstd = rsqrtf(q * INV_VEC - aMean * aMean + 1e-5f);
  }

  auto loadA = [&](int kt) -> float4 {
    const size_t off = (size_t)(m0 + ar) * K + kt + ac;
    float4 r = {0, 0, 0, 0};
    if constexpr (TM == 64) {
      r = *(const float4*)(Ab + off);
    } else {
      const float2 t = *(const float2*)(Ab + off);
      r.x = t.x; r.y = t.y;
    }
    if (ABR) {
      if constexpr (TM == 64) {
        const float4 bz = *(const float4*)(aBias + kt + ac);
        r.x = fmaxf(r.x + bz.x, 0.0f);
        r.y = fmaxf(r.y + bz.y, 0.0f);
        r.z = fmaxf(r.z + bz.z, 0.0f);
        r.w = fmaxf(r.w + bz.w, 0.0f);
      } else {
        const float2 bz = *(const float2*)(aBias + kt + ac);
        r.x = fmaxf(r.x + bz.x, 0.0f);
        r.y = fmaxf(r.y + bz.y, 0.0f);
      }
    }
    if (ALN) {
      r.x = (r.x - aMean) * aRstd;
      r.y = (r.y - aMean) * aRstd;
      r.z = (r.z - aMean) * aRstd;
      r.w = (r.w - aMean) * aRstd;
    }
    return r;
  };
  auto loadB = [&](int kt) -> float4 {
    const size_t off = (size_t)(kt + br) * ldB + nb + bc;
    float4 r = {0, 0, 0, 0};
    if constexpr (TN == 64) {
      r = *(const float4*)(Bsel + off);
    } else {
      const float2 t = *(const float2*)(Bsel + off);
      r.x = t.x; r.y = t.y;
    }
    return r;
  };
  auto stage = [&](float4 a4, float4 b4) {
    As[ac + 0][ar] = a4.x;
    As[ac + 1][ar] = a4.y;
    if constexpr (TM == 64) {
      As[ac + 2][ar] = a4.z;
      As[ac + 3][ar] = a4.w;
    }
    if constexpr (TN == 64) {
      *(float4*)&Bs[br][bc] = b4;
    } else {
      Bs[br][bc] = b4.x;
      Bs[br][bc + 1] = b4.y;
    }
  };

  float acc[MI][NJ] = {};
  float4 a4 = loadA(kBeg);
  float4 b4 = loadB(kBeg);

  for (int kt = kBeg; kt < kEnd; kt += 16) {
    __syncthreads();
    stage(a4, b4);
    __syncthreads();
    if (kt + 16 < kEnd) {  // prefetch next tile under compute
      a4 = loadA(kt + 16);
      b4 = loadB(kt + 16);
    }
#pragma unroll
    for (int kk = 0; kk < 16; ++kk) {
      float a[MI], b[NJ];
      if constexpr (MI == 4) {
        const float4 av = *(const float4*)&As[kk][ty << 2];
        a[0] = av.x; a[1] = av.y; a[2] = av.z; a[3] = av.w;
      } else {
        const float2 av = *(const float2*)&As[kk][ty << 1];
        a[0] = av.x; a[1] = av.y;
      }
      if constexpr (NJ == 4) {
        const float4 bv = *(const float4*)&Bs[kk][tx << 2];
        b[0] = bv.x; b[1] = bv.y; b[2] = bv.z; b[3] = bv.w;
      } else {
        const float2 bv = *(const float2*)&Bs[kk][tx << 1];
        b[0] = bv.x; b[1] = bv.y;
      }
#pragma unroll
      for (int i = 0; i < MI; ++i)
#pragma unroll
        for (int j = 0; j < NJ; ++j) acc[i][j] = fmaf(a[i], b[j], acc[i][j]);
    }
  }

#pragma unroll
  for (int i = 0; i < MI; ++i) {
    const int m = m0 + ty * MI + i;
    float mean = 0.0f, rstd = 1.0f;
    if (RESLN) {
      const float s = Ssum[m], q = Ssq[m];
      mean = s * INV_VEC;
      rstd = rsqrtf(q * INV_VEC - mean * mean + 1e-5f);
    }
    float rs = 0.0f, rq = 0.0f;
#pragma unroll
    for (int j = 0; j < NJ; ++j) {
      const int n = n0 + tx * NJ + j;
      float v = acc[i][j];
      if (OBIAS) v += oBias[n];
      if (RESP) v += resb[(size_t)m * N + n];
      if (RESLN) v += (resb[(size_t)m * N + n] - mean) * rstd;
      if (CATOMIC) atomicAdd(&Cb[(size_t)m * N + n], v);
      else Cb[(size_t)m * N + n] = v;
      if (STATS) { rs += v; rq = fmaf(v, v, rq); }
    }
    if (STATS) {
#pragma unroll
      for (int msk = 1; msk < 16; msk <<= 1) {
        rs += __shfl_xor(rs, msk, 64);
        rq += __shfl_xor(rq, msk, 64);
      }
      if ((tid & 15) == 0) {
        const int rowg = (MODE == 2 ? z * SS : 0) + m;
        atomicAdd(&Ssum[rowg], rs);
        atomicAdd(&Ssq[rowg], rq);
      }
    }
  }
}

// ---------------------------------------------------------------------------
// Reduce NPART QK partials [1024][256] (cols 0..127=Q, 128..255=K) into
// Qd[1024][128] + KT[b][h][j]. Each block also zeroes its 128-float slice of
// Hd (FC1 atomic dest); blocks 0..7 zero the 2048-float stats buffer.
// ---------------------------------------------------------------------------
__global__ __launch_bounds__(256) void qksum_k(const float* __restrict__ QKp,
                                               long ps,
                                               float* __restrict__ Qd,
                                               float* __restrict__ KT,
                                               float* __restrict__ Hd,
                                               float* __restrict__ stats) {
  const int r = blockIdx.x, tid = threadIdx.x;
  if (r < 8) stats[r * 256 + tid] = 0.0f;
  if (tid < 128) Hd[(size_t)r * 128 + tid] = 0.0f;
  const int b = r >> 8, j = r & 255;
  const size_t off = (size_t)r * 256 + tid;
  float v = 0.0f;
#pragma unroll
  for (int p = 0; p < NPART; ++p) v += QKp[(long)p * ps + off];
  if (tid < 128) {
    Qd[(size_t)r * 128 + tid] = v;
  } else {
    KT[(size_t)b * 32768 + (size_t)(tid - 128) * 256 + j] = v;
  }
}

// ---------------------------------------------------------------------------
// Scores + softmax, layers 1-3. Grid (256, B) = 1024 blocks (1 q-row each,
// 4 blocks/CU). Lane j reads KT[b][h][j] -> coalesced.
// ---------------------------------------------------------------------------
__global__ __launch_bounds__(256) void scores1_k(const float* __restrict__ Qd,
                                                 const float* __restrict__ KT,
                                                 const float* __restrict__ wv,
                                                 float* __restrict__ attn) {
  const int b = blockIdx.y, i = blockIdx.x, tid = threadIdx.x;
  __shared__ float qs[128], wvs[128], red[4];
  if (tid < 128) {
    qs[tid] = Qd[(size_t)(b * 256 + i) * 128 + tid];
    wvs[tid] = wv[tid];
  }
  __syncthreads();

  const float* KTb = KT + (size_t)b * 32768 + tid;
  float s = 0.0f;
#pragma unroll 4
  for (int h = 0; h < 128; h += 4) {
    s += wvs[h + 0] * ftanh(qs[h + 0] + KTb[(h + 0) * 256]);
    s += wvs[h + 1] * ftanh(qs[h + 1] + KTb[(h + 1) * 256]);
    s += wvs[h + 2] * ftanh(qs[h + 2] + KTb[(h + 2) * 256]);
    s += wvs[h + 3] * ftanh(qs[h + 3] + KTb[(h + 3) * 256]);
  }
  const float mx = blockMax(s, red);
  const float e = __expf(s - mx);
  const float tot = blockSum(e, red);
  attn[(size_t)(b * 256 + i) * 256 + tid] = e / tot;
}

// ---------------------------------------------------------------------------
// Tail: kt4sum (blocks 0..511, 2 rows each) + q4 GEMV (blocks 512..515).
// ---------------------------------------------------------------------------
__global__ __launch_bounds__(256) void kt4q4_k(const float* __restrict__ K4p,
                                               const float* __restrict__ X3,
                                               const float* __restrict__ Wq4,
                                               const int* __restrict__ lys,
                                               float* __restrict__ KT,
                                               float* __restrict__ q4d) {
  __shared__ float partial[256];
  const int vb = blockIdx.x, tid = threadIdx.x;
  if (vb < 512) {
    const int r = vb * 2 + (tid >> 7), h = tid & 127;
    const int b = r >> 8, j = r & 255;
    const size_t off = (size_t)r * 128 + h;
    float v = 0.0f;
#pragma unroll
    for (int p = 0; p < NPART; ++p) v += K4p[(long)p * 131072 + off];
    KT[(size_t)b * 32768 + (size_t)h * 256 + j] = v;
  } else {
    const int b = vb - 512;
    const int lp = lys[0];
    const float* xr = X3 + (size_t)(b * 256 + lp) * VEC;
    const int h = tid & 127, half = tid >> 7;
    float acc = 0.0f;
    const int k0 = half * 640;
    for (int k = k0; k < k0 + 640; ++k)
      acc = fmaf(xr[k], Wq4[(size_t)k * HID + h], acc);
    partial[tid] = acc;
    __syncthreads();
    if (tid < 128) q4d[b * 128 + tid] = partial[tid] + partial[tid + 128];
  }
}

// ---------------------------------------------------------------------------
// Tail: scores4 (recomputed per block, cheap) + PV slice + residual.
// Grid 20: b = blk&3, col-chunk cs = blk>>2.
// ---------------------------------------------------------------------------
__global__ __launch_bounds__(256) void pv4s_k(const float* __restrict__ q4d,
                                              const float* __restrict__ KT,
                                              const float* __restrict__ wv4,
                                              const int* __restrict__ lys,
                                              const float* __restrict__ X3,
                                              float* __restrict__ A4) {
  const int b = blockIdx.x & 3, cs = blockIdx.x >> 2, tid = threadIdx.x;
  __shared__ float qs[128], wvs[128], aw[256], red[4];
  const int lp = lys[0];
  if (tid < 128) {
    qs[tid] = q4d[b * 128 + tid];
    wvs[tid] = wv4[tid];
  }
  __syncthreads();
  const float* KTb = KT + (size_t)b * 32768 + tid;
  float s = 0.0f;
#pragma unroll 4
  for (int h = 0; h < 128; h += 4) {
    s += wvs[h + 0] * ftanh(qs[h + 0] + KTb[(h + 0) * 256]);
    s += wvs[h + 1] * ftanh(qs[h + 1] + KTb[(h + 1) * 256]);
    s += wvs[h + 2] * ftanh(qs[h + 2] + KTb[(h + 2) * 256]);
    s += wvs[h + 3] * ftanh(qs[h + 3] + KTb[(h + 3) * 256]);
  }
  const float mx = blockMax(s, red);
  const float e = __expf(s - mx);
  const float tot = blockSum(e, red);
  aw[tid] = e / tot;
  __syncthreads();

  const int c = cs * 256 + tid;
  const float* Xb = X3 + (size_t)b * SS * VEC;
  float acc = 0.0f;
#pragma unroll 8
  for (int j = 0; j < 256; ++j) acc = fmaf(aw[j], Xb[(size_t)j * VEC + c], acc);
  acc += Xb[(size_t)lp * VEC + c];
  A4[b * VEC + c] = acc;
}

// lnhead: grid (B). LN(A4[b]) then 1280->32(relu)->12(relu)->2 head.
__global__ __launch_bounds__(256) void lnhead_k(
    const float* __restrict__ A4,
    const float* __restrict__ hW1, const float* __restrict__ hb1,
    const float* __restrict__ hW2, const float* __restrict__ hb2,
    const float* __restrict__ hW3, const float* __restrict__ hb3,
    float* __restrict__ out) {
  const int b = blockIdx.x, tid = threadIdx.x;
  __shared__ float xrow[1280], partial[256], red[4];
  __shared__ float h1s[32], h2s[12];
  float v[5];
  float sum = 0.0f;
#pragma unroll
  for (int k = 0; k < 5; ++k) {
    v[k] = A4[b * VEC + tid + k * 256];
    sum += v[k];
  }
  sum = blockSum(sum, red);
  const float m = sum * INV_VEC;
  float sq = 0.0f;
#pragma unroll
  for (int k = 0; k < 5; ++k) {
    const float dl = v[k] - m;
    sq += dl * dl;
  }
  sq = blockSum(sq, red);
  const float rstd = rsqrtf(sq * INV_VEC + 1e-5f);
#pragma unroll
  for (int k = 0; k < 5; ++k) xrow[tid + k * 256] = (v[k] - m) * rstd;
  __syncthreads();
  {
    const int n = tid & 31, sl = tid >> 5;
    float p = 0.0f;
    for (int k = sl * 160; k < sl * 160 + 160; ++k)
      p = fmaf(xrow[k], hW1[(size_t)k * 32 + n], p);
    partial[tid] = p;
  }
  __syncthreads();
  if (tid < 32) {
    float t = 0.0f;
#pragma unroll
    for (int s2 = 0; s2 < 8; ++s2) t += partial[s2 * 32 + tid];
    h1s[tid] = fmaxf(t + hb1[tid], 0.0f);
  }
  __syncthreads();
  if (tid < 12) {
    float t = 0.0f;
#pragma unroll
    for (int k = 0; k < 32; ++k) t = fmaf(h1s[k], hW2[k * 12 + tid], t);
    h2s[tid] = fmaxf(t + hb2[tid], 0.0f);
  }
  __syncthreads();
  if (tid < 2) {
    float t = 0.0f;
#pragma unroll
    for (int k = 0; k < 12; ++k) t = fmaf(h2s[k], hW3[k * 2 + tid], t);
    out[b * 2 + tid] = t + hb3[tid];
  }
}

// ---------------------------------------------------------------------------
extern "C" void kernel_launch(void* const* d_in, const int* in_sizes, int n_in,
                              void* d_out, int out_size, void* d_ws, size_t ws_size,
                              hipStream_t stream) {
  const float* X = (const float*)d_in[0];
  const int* lys = (const int*)d_in[1];
  const float* Wq[4] = {(const float*)d_in[2], (const float*)d_in[5],
                        (const float*)d_in[8], (const float*)d_in[11]};
  const float* Wk[4] = {(const float*)d_in[3], (const float*)d_in[6],
                        (const float*)d_in[9], (const float*)d_in[12]};
  const float* wv[4] = {(const float*)d_in[4], (const float*)d_in[7],
                        (const float*)d_in[10], (const float*)d_in[13]};
  const float* rW1[3] = {(const float*)d_in[14], (const float*)d_in[18],
                         (const float*)d_in[22]};
  const float* rb1[3] = {(const float*)d_in[15], (const float*)d_in[19],
                         (const float*)d_in[23]};
  const float* rW2[3] = {(const float*)d_in[16], (const float*)d_in[20],
                         (const float*)d_in[24]};
  const float* rb2[3] = {(const float*)d_in[17], (const float*)d_in[21],
                         (const float*)d_in[25]};
  const float* hW1 = (const float*)d_in[26];
  const float* hb1 = (const float*)d_in[27];
  const float* hW2 = (const float*)d_in[28];
  const float* hb2 = (const float*)d_in[29];
  const float* hW3 = (const float*)d_in[30];
  const float* hb3 = (const float*)d_in[31];
  float* out = (float*)d_out;

  // Workspace (floats), ~36 MB.
  float* ws = (float*)d_ws;
  const long QK_PS = 262144;                 // QK partial stride (1024*256)
  const long H_PS  = 131072;                 // K4 partial stride (1024*128)
  float* QKp   = ws;                         // NPART x 262144 (K4p reuses)
  float* Qd    = QKp + (long)NPART * QK_PS;  // 1024*128
  float* KT    = Qd + 131072;                // 4*128*256
  float* attn  = KT + 131072;                // 1024*256
  float* Yraw  = attn + 262144;              // 1024*1280
  float* Hd    = Yraw + 1310720;             // 1024*128 (FC1 atomic dest)
  float* buf0  = Hd + 131072;                // 1024*1280
  float* buf1  = buf0 + 1310720;             // 1024*1280
  float* stats = buf1 + 1310720;             // 2048 (sum[1024], sumsq[1024])
  float* q4d   = stats + 2048;               // 4*128
  float* A4    = q4d + 512;                  // 4*1280
  float* Ssum = stats, *Ssq = stats + 1024;

  const int NSPLIT_NONE = 1 << 30;
  const float* P[3] = {X, buf0, buf1};
  float* Q[3] = {buf0, buf1, buf0};

  for (int l = 0; l < 3; ++l) {
    const float* Xin = P[l];
    // QKp[z] = Xin @ [Wq|Wk] over K-slice z (16 x 80). 1024 blocks.
    gemm_k<64, 64, 4, 4, 1, false, false, false, false, false, false, false>
        <<<dim3(4, 16, NPART), 256, 0, stream>>>(
            Xin, 0, Wq[l], Wk[l], HID, 0, HID, QKp, QK_PS, nullptr, nullptr,
            nullptr, nullptr, nullptr, 256, VEC, 80);
    // Reduce partials -> Qd + KT; zero stats + Hd. 1024 blocks.
    qksum_k<<<dim3(MROWS), 256, 0, stream>>>(QKp, QK_PS, Qd, KT, Hd, stats);
    // attn = softmax(wv . tanh(q_i + k_j)). 1024 blocks.
    scores1_k<<<dim3(SS, BB), 256, 0, stream>>>(Qd, KT, wv[l], attn);
    // Yraw = attn @ Xin + Xin (batched, residual) + row stats. 640 blocks.
    gemm_k<64, 32, 4, 2, 2, false, false, false, false, true, true, false>
        <<<dim3(40, 4, BB), 256, 0, stream>>>(
            attn, (long)SS * SS, Xin, Xin, NSPLIT_NONE, (long)SS * VEC, VEC,
            Yraw, (long)SS * VEC, nullptr, nullptr, Xin, Ssum, Ssq,
            VEC, SS, 0);
    // Hd += LN(Yraw) @ rW1 (split-K=16, atomic into dense Hd). 512 blocks.
    gemm_k<64, 64, 4, 4, 1, false, true, false, false, false, false, true>
        <<<dim3(2, 16, NPART), 256, 0, stream>>>(
            Yraw, 0, rW1[l], rW1[l], NSPLIT_NONE, 0, HID, Hd, 0, nullptr,
            nullptr, nullptr, Ssum, Ssq, HID, VEC, 80);
    // Xout = relu(Hd+b1) @ rW2 + b2 + LN(Yraw). 640 blocks (32x64 tiles).
    gemm_k<32, 64, 2, 4, 0, true, false, true, true, false, false, false>
        <<<dim3(20, 32, 1), 256, 0, stream>>>(
            Hd, 0, rW2[l], rW2[l], NSPLIT_NONE, 0, VEC, Q[l], 0, rb1[l],
            rb2[l], Yraw, Ssum, Ssq, VEC, HID, 0);
  }

  const float* X3 = Q[2];  // buf0
  // Layer 4: K-proj split-K=16 (partials into QKp region). 512 blocks.
  gemm_k<64, 64, 4, 4, 1, false, false, false, false, false, false, false>
      <<<dim3(2, 16, NPART), 256, 0, stream>>>(
          X3, 0, Wk[3], Wk[3], NSPLIT_NONE, 0, HID, QKp, H_PS, nullptr,
          nullptr, nullptr, nullptr, nullptr, HID, VEC, 80);
  // kt4sum + q4 GEMV. 516 blocks.
  kt4q4_k<<<dim3(516), 256, 0, stream>>>(QKp, X3, Wq[3], lys, KT, q4d);
  // scores4 (recomputed) + PV slice + residual. 20 blocks.
  pv4s_k<<<dim3(20), 256, 0, stream>>>(q4d, KT, wv[3], lys, X3, A4);
  // LN + head. 4 blocks.
  lnhead_k<<<dim3(BB), 256, 0, stream>>>(A4, hW1, hb1, hW2, hb2, hW3, hb3, out);
}

// Round 9
// 453.731 us; speedup vs baseline: 1.0817x; 1.0817x over previous
//
#include <hip/hip_runtime.h>

// AttentionBasedNN: 4-layer additive attention + residual FCs + head.
// VEC=1280, HID=128, B=4, S=256. fp32 (no fp32 MFMA on CDNA4 -> vector ALU).
//
// Round-9: R7's 22-dispatch structure (best-proven) with a restructured
// GEMM inner loop: LDS double-buffer, ONE barrier per K-iter, and 2-tile-
// ahead register prefetch (load for tile i+2 issued while computing tile i).
// Split-K=8, FC1 -> disjoint Hp partials (no atomics), LN folded via stats.

#define DEV __device__ __forceinline__

static constexpr int VEC = 1280;
static constexpr int HID = 128;
static constexpr int BB  = 4;
static constexpr int SS  = 256;
static constexpr int MROWS = BB * SS;   // 1024
static constexpr int NPART = 8;         // split-K partials (QK, FC1, K4)
static constexpr float INV_VEC = 1.0f / 1280.0f;

DEV float ftanh(float x) {
  float e = __expf(2.0f * x);
  return 1.0f - __fdividef(2.0f, e + 1.0f);
}

DEV float waveSum(float v) {
#pragma unroll
  for (int off = 32; off > 0; off >>= 1) v += __shfl_xor(v, off, 64);
  return v;
}
DEV float waveMax(float v) {
#pragma unroll
  for (int off = 32; off > 0; off >>= 1) v = fmaxf(v, __shfl_xor(v, off, 64));
  return v;
}
// blockDim.x == 256 (4 waves) everywhere these are used.
DEV float blockSum(float v, float* red) {
  v = waveSum(v);
  int tid = threadIdx.x;
  if ((tid & 63) == 0) red[tid >> 6] = v;
  __syncthreads();
  float r = (red[0] + red[1]) + (red[2] + red[3]);
  __syncthreads();
  return r;
}
DEV float blockMax(float v, float* red) {
  v = waveMax(v);
  int tid = threadIdx.x;
  if ((tid & 63) == 0) red[tid >> 6] = v;
  __syncthreads();
  float r = fmaxf(fmaxf(red[0], red[1]), fmaxf(red[2], red[3]));
  __syncthreads();
  return r;
}

// ---------------------------------------------------------------------------
// fp32 GEMM, 64x64 tile, BK=16, 256 threads, 4x4 microtile.
// NEW: double-buffered LDS (one __syncthreads per K-iter) + 2-deep register
// prefetch: at iter i we stage tile i+1 into LDS[^buf] and issue the global
// loads for tile i+2. Load-to-use slack ~= 1.5 iterations (hides L2 latency).
// MODE 0 plain | 1 split-K (z: k-slice kChunk, C += z*sCb disjoint partials)
//      | 2 batched (z: A += z*sAb, B += z*sBb, C/res += z*sCb).
// AFUSE: A = relu(sum of NPART partials (stride aPart) + aBias[k]).
// ALN:   A = (A - mean[row]) * rstd[row] from stats (row = m0+ar).
// OBIAS += oBias[n]. RESP += res[m][n]. RESLN += LN(res[m][n]) via stats.
// STATS: epilogue row sum/sumsq -> atomicAdd Ssum/Ssq (row = batchoff + m).
// ---------------------------------------------------------------------------
template <int MODE, bool AFUSE, bool ALN, bool OBIAS, bool RESLN, bool RESP,
          bool STATS>
__global__ __launch_bounds__(256) void gemm_k(
    const float* __restrict__ A, long sAb, long aPart,
    const float* __restrict__ B0, const float* __restrict__ B1, int nSplitB,
    long sBb, int ldB,
    float* __restrict__ C, long sCb,
    const float* __restrict__ aBias, const float* __restrict__ oBias,
    const float* __restrict__ res,
    float* __restrict__ Ssum, float* __restrict__ Ssq,
    int N, int K, int kChunk) {
  const int n0 = blockIdx.x * 64;
  const int m0 = blockIdx.y * 64;
  const int z  = blockIdx.z;

  const float* Ab = A + (MODE == 2 ? (long)z * sAb : 0L);
  float*       Cb = C + (MODE >= 1 ? (long)z * sCb : 0L);
  const float* resb = (RESP || RESLN)
                          ? (res + (MODE == 2 ? (long)z * sCb : 0L))
                          : nullptr;
  const float* Bsel;
  int nb;
  if (n0 < nSplitB) { Bsel = B0; nb = n0; } else { Bsel = B1; nb = n0 - nSplitB; }
  if (MODE == 2) Bsel += (long)z * sBb;

  const int kBeg = (MODE == 1) ? z * kChunk : 0;
  const int kEnd = (MODE == 1) ? kBeg + kChunk : K;
  const int nIter = (kEnd - kBeg) >> 4;

  __shared__ float As[2][16][68];  // [buf][k][m]
  __shared__ float Bs[2][16][68];  // [buf][k][n]

  const int tid = threadIdx.x;
  const int tx = tid & 15, ty = tid >> 4;
  const int ar = tid >> 2, ac = (tid & 3) << 2;   // A: row 0..63, k {0,4,8,12}
  const int br = tid >> 4, bc = (tid & 15) << 2;  // B: k-row 0..15, col 0..60

  float aMean = 0.0f, aRstd = 1.0f;
  if (ALN) {
    const int rm = m0 + ar;
    const float s = Ssum[rm], q = Ssq[rm];
    aMean = s * INV_VEC;
    aRstd = rsqrtf(q * INV_VEC - aMean * aMean + 1e-5f);
  }

  auto loadA = [&](int kt) -> float4 {
    const size_t off = (size_t)(m0 + ar) * K + kt + ac;
    float4 s = *(const float4*)(Ab + off);
    if (AFUSE) {
#pragma unroll
      for (int p2 = 1; p2 < NPART; ++p2) {
        const float4 t2 = *(const float4*)(Ab + (long)p2 * aPart + off);
        s.x += t2.x; s.y += t2.y; s.z += t2.z; s.w += t2.w;
      }
      const float4 bz = *(const float4*)(aBias + kt + ac);
      s.x = fmaxf(s.x + bz.x, 0.0f);
      s.y = fmaxf(s.y + bz.y, 0.0f);
      s.z = fmaxf(s.z + bz.z, 0.0f);
      s.w = fmaxf(s.w + bz.w, 0.0f);
    }
    if (ALN) {
      s.x = (s.x - aMean) * aRstd;
      s.y = (s.y - aMean) * aRstd;
      s.z = (s.z - aMean) * aRstd;
      s.w = (s.w - aMean) * aRstd;
    }
    return s;
  };
  auto loadB = [&](int kt) -> float4 {
    return *(const float4*)(Bsel + (size_t)(kt + br) * ldB + nb + bc);
  };
  auto stage = [&](int buf, float4 a4, float4 b4) {
    As[buf][ac + 0][ar] = a4.x;
    As[buf][ac + 1][ar] = a4.y;
    As[buf][ac + 2][ar] = a4.z;
    As[buf][ac + 3][ar] = a4.w;
    *(float4*)&Bs[buf][br][bc] = b4;
  };

  float acc[4][4] = {};

  // Pipeline prologue: tile 0 staged; tile 1 in registers.
  float4 aNxt = {0, 0, 0, 0}, bNxt = {0, 0, 0, 0};
  {
    const float4 a0 = loadA(kBeg);
    const float4 b0 = loadB(kBeg);
    if (nIter > 1) { aNxt = loadA(kBeg + 16); bNxt = loadB(kBeg + 16); }
    stage(0, a0, b0);
  }

  for (int it = 0; it < nIter; ++it) {
    __syncthreads();  // LDS[it&1] staged; prior reads of LDS[(it+1)&1] done
    const int cur = it & 1;
    if (it + 1 < nIter) {
      stage(cur ^ 1, aNxt, bNxt);  // stage tile it+1 into the other buffer
      if (it + 2 < nIter) {        // issue loads for tile it+2 (2-deep)
        aNxt = loadA(kBeg + (it + 2) * 16);
        bNxt = loadB(kBeg + (it + 2) * 16);
      }
    }
#pragma unroll
    for (int kk = 0; kk < 16; ++kk) {
      const float4 av = *(const float4*)&As[cur][kk][ty << 2];
      const float4 bv = *(const float4*)&Bs[cur][kk][tx << 2];
      const float a[4] = {av.x, av.y, av.z, av.w};
      const float b[4] = {bv.x, bv.y, bv.z, bv.w};
#pragma unroll
      for (int i = 0; i < 4; ++i)
#pragma unroll
        for (int j = 0; j < 4; ++j) acc[i][j] = fmaf(a[i], b[j], acc[i][j]);
    }
  }

  float rs[4], rq[4];
#pragma unroll
  for (int i = 0; i < 4; ++i) {
    const int m = m0 + (ty << 2) + i;
    float mean = 0.0f, rstd = 1.0f;
    if (RESLN) {
      const float s = Ssum[m], q = Ssq[m];
      mean = s * INV_VEC;
      rstd = rsqrtf(q * INV_VEC - mean * mean + 1e-5f);
    }
    if (STATS) { rs[i] = 0.0f; rq[i] = 0.0f; }
#pragma unroll
    for (int j = 0; j < 4; ++j) {
      const int n = n0 + (tx << 2) + j;
      float v = acc[i][j];
      if (OBIAS) v += oBias[n];
      if (RESP) v += resb[(size_t)m * N + n];
      if (RESLN) v += (resb[(size_t)m * N + n] - mean) * rstd;
      Cb[(size_t)m * N + n] = v;
      if (STATS) { rs[i] += v; rq[i] = fmaf(v, v, rq[i]); }
    }
  }
  if (STATS) {
#pragma unroll
    for (int i = 0; i < 4; ++i) {
      float s = rs[i], q = rq[i];
#pragma unroll
      for (int msk = 1; msk < 16; msk <<= 1) {
        s += __shfl_xor(s, msk, 64);
        q += __shfl_xor(q, msk, 64);
      }
      if ((tid & 15) == 0) {
        const int rowg = (MODE == 2 ? z * SS : 0) + m0 + (ty << 2) + i;
        atomicAdd(&Ssum[rowg], s);
        atomicAdd(&Ssq[rowg], q);
      }
    }
  }
}

// ---------------------------------------------------------------------------
// Reduce NPART QK partials [1024][256] (cols 0..127=Q, 128..255=K) into
// Qd[1024][128] + KT[b][h][j]; blocks 0..7 also zero the stats buffer.
// ---------------------------------------------------------------------------
__global__ __launch_bounds__(256) void qksum_k(const float* __restrict__ QKp,
                                               long ps,
                                               float* __restrict__ Qd,
                                               float* __restrict__ KT,
                                               float* __restrict__ stats) {
  const int r = blockIdx.x, tid = threadIdx.x;
  if (r < 8) stats[r * 256 + tid] = 0.0f;
  const int b = r >> 8, j = r & 255;
  const size_t off = (size_t)r * 256 + tid;
  float v = 0.0f;
#pragma unroll
  for (int p = 0; p < NPART; ++p) v += QKp[(long)p * ps + off];
  if (tid < 128) {
    Qd[(size_t)r * 128 + tid] = v;
  } else {
    KT[(size_t)b * 32768 + (size_t)(tid - 128) * 256 + j] = v;
  }
}

// ---------------------------------------------------------------------------
// Scores + softmax, layers 1-3. Grid (128, B) = 512 blocks (2 q-rows each).
// Lane j reads KT[b][h][j] -> coalesced.
// ---------------------------------------------------------------------------
__global__ __launch_bounds__(256) void scores2_k(const float* __restrict__ Qd,
                                                 const float* __restrict__ KT,
                                                 const float* __restrict__ wv,
                                                 float* __restrict__ attn) {
  const int b = blockIdx.y, i0 = blockIdx.x * 2, tid = threadIdx.x;
  __shared__ float qs[2][128], wvs[128], red[4];
  {
    const int rr = tid >> 7, h = tid & 127;
    qs[rr][h] = Qd[(size_t)(b * 256 + i0 + rr) * 128 + h];
  }
  if (tid < 128) wvs[tid] = wv[tid];
  __syncthreads();

  const float* KTb = KT + (size_t)b * 32768 + tid;
  float s0 = 0.0f, s1 = 0.0f;
#pragma unroll 4
  for (int h = 0; h < 128; h += 4) {
    const float k0 = KTb[(h + 0) * 256];
    const float k1 = KTb[(h + 1) * 256];
    const float k2 = KTb[(h + 2) * 256];
    const float k3 = KTb[(h + 3) * 256];
    const float w0 = wvs[h], w1 = wvs[h + 1], w2 = wvs[h + 2], w3 = wvs[h + 3];
    s0 += w0 * ftanh(qs[0][h] + k0) + w1 * ftanh(qs[0][h + 1] + k1) +
          w2 * ftanh(qs[0][h + 2] + k2) + w3 * ftanh(qs[0][h + 3] + k3);
    s1 += w0 * ftanh(qs[1][h] + k0) + w1 * ftanh(qs[1][h + 1] + k1) +
          w2 * ftanh(qs[1][h + 2] + k2) + w3 * ftanh(qs[1][h + 3] + k3);
  }
  {
    const float mx = blockMax(s0, red);
    const float e = __expf(s0 - mx);
    const float tot = blockSum(e, red);
    attn[(size_t)(b * 256 + i0) * 256 + tid] = e / tot;
  }
  {
    const float mx = blockMax(s1, red);
    const float e = __expf(s1 - mx);
    const float tot = blockSum(e, red);
    attn[(size_t)(b * 256 + i0 + 1) * 256 + tid] = e / tot;
  }
}

// ---------------------------------------------------------------------------
// Tail: kt4sum (blocks 0..511, 2 rows each) + q4 GEMV (blocks 512..515).
// ---------------------------------------------------------------------------
__global__ __launch_bounds__(256) void kt4q4_k(const float* __restrict__ K4p,
                                               const float* __restrict__ X3,
                                               const float* __restrict__ Wq4,
                                               const int* __restrict__ lys,
                                               float* __restrict__ KT,
                                               float* __restrict__ q4d) {
  __shared__ float partial[256];
  const int vb = blockIdx.x, tid = threadIdx.x;
  if (vb < 512) {
    const int r = vb * 2 + (tid >> 7), h = tid & 127;
    const int b = r >> 8, j = r & 255;
    const size_t off = (size_t)r * 128 + h;
    float v = 0.0f;
#pragma unroll
    for (int p = 0; p < NPART; ++p) v += K4p[(long)p * 131072 + off];
    KT[(size_t)b * 32768 + (size_t)h * 256 + j] = v;
  } else {
    const int b = vb - 512;
    const int lp = lys[0];
    const float* xr = X3 + (size_t)(b * 256 + lp) * VEC;
    const int h = tid & 127, half = tid >> 7;
    float acc = 0.0f;
    const int k0 = half * 640;
    for (int k = k0; k < k0 + 640; ++k)
      acc = fmaf(xr[k], Wq4[(size_t)k * HID + h], acc);
    partial[tid] = acc;
    __syncthreads();
    if (tid < 128) q4d[b * 128 + tid] = partial[tid] + partial[tid + 128];
  }
}

// ---------------------------------------------------------------------------
// Tail: scores4 (recomputed per block, cheap) + PV slice + residual.
// Grid 20: b = blk&3, col-chunk cs = blk>>2.
// ---------------------------------------------------------------------------
__global__ __launch_bounds__(256) void pv4s_k(const float* __restrict__ q4d,
                                              const float* __restrict__ KT,
                                              const float* __restrict__ wv4,
                                              const int* __restrict__ lys,
                                              const float* __restrict__ X3,
                                              float* __restrict__ A4) {
  const int b = blockIdx.x & 3, cs = blockIdx.x >> 2, tid = threadIdx.x;
  __shared__ float qs[128], wvs[128], aw[256], red[4];
  const int lp = lys[0];
  if (tid < 128) {
    qs[tid] = q4d[b * 128 + tid];
    wvs[tid] = wv4[tid];
  }
  __syncthreads();
  const float* KTb = KT + (size_t)b * 32768 + tid;
  float s = 0.0f;
#pragma unroll 4
  for (int h = 0; h < 128; h += 4) {
    s += wvs[h + 0] * ftanh(qs[h + 0] + KTb[(h + 0) * 256]);
    s += wvs[h + 1] * ftanh(qs[h + 1] + KTb[(h + 1) * 256]);
    s += wvs[h + 2] * ftanh(qs[h + 2] + KTb[(h + 2) * 256]);
    s += wvs[h + 3] * ftanh(qs[h + 3] + KTb[(h + 3) * 256]);
  }
  const float mx = blockMax(s, red);
  const float e = __expf(s - mx);
  const float tot = blockSum(e, red);
  aw[tid] = e / tot;
  __syncthreads();

  const int c = cs * 256 + tid;
  const float* Xb = X3 + (size_t)b * SS * VEC;
  float acc = 0.0f;
#pragma unroll 8
  for (int j = 0; j < 256; ++j) acc = fmaf(aw[j], Xb[(size_t)j * VEC + c], acc);
  acc += Xb[(size_t)lp * VEC + c];
  A4[b * VEC + c] = acc;
}

// lnhead: grid (B). LN(A4[b]) then 1280->32(relu)->12(relu)->2 head.
__global__ __launch_bounds__(256) void lnhead_k(
    const float* __restrict__ A4,
    const float* __restrict__ hW1, const float* __restrict__ hb1,
    const float* __restrict__ hW2, const float* __restrict__ hb2,
    const float* __restrict__ hW3, const float* __restrict__ hb3,
    float* __restrict__ out) {
  const int b = blockIdx.x, tid = threadIdx.x;
  __shared__ float xrow[1280], partial[256], red[4];
  __shared__ float h1s[32], h2s[12];
  float v[5];
  float sum = 0.0f;
#pragma unroll
  for (int k = 0; k < 5; ++k) {
    v[k] = A4[b * VEC + tid + k * 256];
    sum += v[k];
  }
  sum = blockSum(sum, red);
  const float m = sum * INV_VEC;
  float sq = 0.0f;
#pragma unroll
  for (int k = 0; k < 5; ++k) {
    const float dl = v[k] - m;
    sq += dl * dl;
  }
  sq = blockSum(sq, red);
  const float rstd = rsqrtf(sq * INV_VEC + 1e-5f);
#pragma unroll
  for (int k = 0; k < 5; ++k) xrow[tid + k * 256] = (v[k] - m) * rstd;
  __syncthreads();
  {
    const int n = tid & 31, sl = tid >> 5;
    float p = 0.0f;
    for (int k = sl * 160; k < sl * 160 + 160; ++k)
      p = fmaf(xrow[k], hW1[(size_t)k * 32 + n], p);
    partial[tid] = p;
  }
  __syncthreads();
  if (tid < 32) {
    float t = 0.0f;
#pragma unroll
    for (int s2 = 0; s2 < 8; ++s2) t += partial[s2 * 32 + tid];
    h1s[tid] = fmaxf(t + hb1[tid], 0.0f);
  }
  __syncthreads();
  if (tid < 12) {
    float t = 0.0f;
#pragma unroll
    for (int k = 0; k < 32; ++k) t = fmaf(h1s[k], hW2[k * 12 + tid], t);
    h2s[tid] = fmaxf(t + hb2[tid], 0.0f);
  }
  __syncthreads();
  if (tid < 2) {
    float t = 0.0f;
#pragma unroll
    for (int k = 0; k < 12; ++k) t = fmaf(h2s[k], hW3[k * 2 + tid], t);
    out[b * 2 + tid] = t + hb3[tid];
  }
}

// ---------------------------------------------------------------------------
extern "C" void kernel_launch(void* const* d_in, const int* in_sizes, int n_in,
                              void* d_out, int out_size, void* d_ws, size_t ws_size,
                              hipStream_t stream) {
  const float* X = (const float*)d_in[0];
  const int* lys = (const int*)d_in[1];
  const float* Wq[4] = {(const float*)d_in[2], (const float*)d_in[5],
                        (const float*)d_in[8], (const float*)d_in[11]};
  const float* Wk[4] = {(const float*)d_in[3], (const float*)d_in[6],
                        (const float*)d_in[9], (const float*)d_in[12]};
  const float* wv[4] = {(const float*)d_in[4], (const float*)d_in[7],
                        (const float*)d_in[10], (const float*)d_in[13]};
  const float* rW1[3] = {(const float*)d_in[14], (const float*)d_in[18],
                         (const float*)d_in[22]};
  const float* rb1[3] = {(const float*)d_in[15], (const float*)d_in[19],
                         (const float*)d_in[23]};
  const float* rW2[3] = {(const float*)d_in[16], (const float*)d_in[20],
                         (const float*)d_in[24]};
  const float* rb2[3] = {(const float*)d_in[17], (const float*)d_in[21],
                         (const float*)d_in[25]};
  const float* hW1 = (const float*)d_in[26];
  const float* hb1 = (const float*)d_in[27];
  const float* hW2 = (const float*)d_in[28];
  const float* hb2 = (const float*)d_in[29];
  const float* hW3 = (const float*)d_in[30];
  const float* hb3 = (const float*)d_in[31];
  float* out = (float*)d_out;

  // Workspace (floats), ~30 MB.
  float* ws = (float*)d_ws;
  const long QK_PS = 262144;                 // QK partial stride (1024*256)
  const long H_PS  = 131072;                 // FC1/K4 partial stride (1024*128)
  float* QKp   = ws;                         // NPART x 262144 (K4p reuses)
  float* Qd    = QKp + (long)NPART * QK_PS;  // 1024*128
  float* KT    = Qd + 131072;                // 4*128*256
  float* attn  = KT + 131072;                // 1024*256
  float* Yraw  = attn + 262144;              // 1024*1280
  float* Hp    = Yraw + 1310720;             // NPART x 131072
  float* buf0  = Hp + (long)NPART * H_PS;    // 1024*1280
  float* buf1  = buf0 + 1310720;             // 1024*1280
  float* stats = buf1 + 1310720;             // 2048 (sum[1024], sumsq[1024])
  float* q4d   = stats + 2048;               // 4*128
  float* A4    = q4d + 512;                  // 4*1280
  float* Ssum = stats, *Ssq = stats + 1024;

  const int NSPLIT_NONE = 1 << 30;
  const float* P[3] = {X, buf0, buf1};
  float* Q[3] = {buf0, buf1, buf0};

  for (int l = 0; l < 3; ++l) {
    const float* Xin = P[l];
    // QKp[z] = Xin @ [Wq|Wk] over K-slice z. 512 blocks.
    gemm_k<1, false, false, false, false, false, false>
        <<<dim3(4, 16, NPART), 256, 0, stream>>>(
            Xin, 0, 0, Wq[l], Wk[l], HID, 0, HID, QKp, QK_PS, nullptr, nullptr,
            nullptr, nullptr, nullptr, 256, VEC, 160);
    // Reduce partials -> Qd + KT; zero stats. 1024 blocks.
    qksum_k<<<dim3(MROWS), 256, 0, stream>>>(QKp, QK_PS, Qd, KT, stats);
    // attn = softmax(wv . tanh(q_i + k_j)). 512 blocks.
    scores2_k<<<dim3(128, BB), 256, 0, stream>>>(Qd, KT, wv[l], attn);
    // Yraw = attn @ Xin + Xin (batched, residual fused) + row stats. 320 blocks.
    gemm_k<2, false, false, false, false, true, true>
        <<<dim3(20, 4, BB), 256, 0, stream>>>(
            attn, (long)SS * SS, 0, Xin, Xin, NSPLIT_NONE, (long)SS * VEC, VEC,
            Yraw, (long)SS * VEC, nullptr, nullptr, Xin, Ssum, Ssq,
            VEC, SS, 0);
    // Hp[z] = LN(Yraw) @ rW1 (LN folded into A-load). 256 blocks.
    gemm_k<1, false, true, false, false, false, false>
        <<<dim3(2, 16, NPART), 256, 0, stream>>>(
            Yraw, 0, 0, rW1[l], rW1[l], NSPLIT_NONE, 0, HID, Hp, H_PS, nullptr,
            nullptr, nullptr, Ssum, Ssq, HID, VEC, 160);
    // Xout = relu(sum(Hp)+b1) @ rW2 + b2 + LN(Yraw). 320 blocks.
    gemm_k<0, true, false, true, true, false, false>
        <<<dim3(20, 16, 1), 256, 0, stream>>>(
            Hp, 0, H_PS, rW2[l], rW2[l], NSPLIT_NONE, 0, VEC, Q[l], 0, rb1[l],
            rb2[l], Yraw, Ssum, Ssq, VEC, HID, 0);
  }

  const float* X3 = Q[2];  // buf0
  // Layer 4: K-proj split-K (partials into QKp region). 256 blocks.
  gemm_k<1, false, false, false, false, false, false>
      <<<dim3(2, 16, NPART), 256, 0, stream>>>(
          X3, 0, 0, Wk[3], Wk[3], NSPLIT_NONE, 0, HID, QKp, H_PS, nullptr,
          nullptr, nullptr, nullptr, nullptr, HID, VEC, 160);
  // kt4sum + q4 GEMV. 516 blocks.
  kt4q4_k<<<dim3(516), 256, 0, stream>>>(QKp, X3, Wq[3], lys, KT, q4d);
  // scores4 (recomputed) + PV slice + residual. 20 blocks.
  pv4s_k<<<dim3(20), 256, 0, stream>>>(q4d, KT, wv[3], lys, X3, A4);
  // LN + head. 4 blocks.
  lnhead_k<<<dim3(BB), 256, 0, stream>>>(A4, hW1, hb1, hW2, hb2, hW3, hb3, out);
}